// Round 2
// baseline (101.746 us; speedup 1.0000x reference)
//
#include <hip/hip_runtime.h>

// Problem dims (fixed by reference setup_inputs)
#define BDIM 256
#define IDIM 1024
#define ODIM 1024

#define TILE_O 64             // outputs per block (one per lane)
#define TILE_B 4              // batch rows per thread
#define NW 8                  // waves per block, each owns an i-eighth
#define QLEN (IDIM / NW)      // 128 i per wave
#define CHUNK 8               // i per prefetch chunk
#define NCHUNK (QLEN / CHUNK) // 16 chunks

#if __has_builtin(__builtin_amdgcn_exp2f)
#define FAST_EXP2(v) __builtin_amdgcn_exp2f(v)
#else
#define FAST_EXP2(v) exp2f(v)
#endif

__global__ __launch_bounds__(512, 8)
void stl_kernel(const float* __restrict__ x,
                const float* __restrict__ w,
                const float* __restrict__ bias,
                float* __restrict__ out) {
  // LDS only for the cross-wave combine (16 KB). No x staging, no barrier #1.
  __shared__ float ps[NW][TILE_O][8];

  const int tx = threadIdx.x;          // 0..63 -> output column (lane)
  const int ty = threadIdx.y;          // 0..7  -> i-eighth (one wave each)
  const int o0 = blockIdx.x * TILE_O;
  const int b0 = blockIdx.y * TILE_B;

  // Force ty scalar so the whole x-address chain is provably wave-uniform:
  // the compiler then selects s_load (SMEM) for the x reads -> zero LDS/VMEM
  // pressure for the broadcast operand, consumed as v_mul v, s, v.
  const int tyu = __builtin_amdgcn_readfirstlane(ty);
  const int qbase = tyu * QLEN;

  const float* bx = x + (size_t)b0 * IDIM + qbase;       // uniform base
  const float* wp = w + (size_t)qbase * ODIM + o0 + tx;  // per-lane column

  const float LOG2E = 1.4426950408889634f;  // folds 1/TEMPERATURE too

  // All indices inside these macros are compile-time constants (rule #20):
  // xdst[r][u], wdst[u] stay in registers; only the chunk index cc is runtime.
#define XLOAD(xdst, cc)                                                   \
  _Pragma("unroll")                                                       \
  for (int r = 0; r < TILE_B; ++r) {                                      \
    _Pragma("unroll")                                                     \
    for (int u = 0; u < CHUNK; ++u)                                       \
      xdst[r][u] = bx[(size_t)r * IDIM + (size_t)(cc) * CHUNK + u];       \
  }

#define WLOAD(wdst, cc)                                                   \
  {                                                                       \
    const float* wq = wp + (size_t)((cc) * CHUNK) * ODIM;                 \
    _Pragma("unroll")                                                     \
    for (int u = 0; u < CHUNK; ++u) wdst[u] = wq[(size_t)u * ODIM];       \
  }

#define COMPUTE(xc, wc)                                                   \
  _Pragma("unroll")                                                       \
  for (int u = 0; u < CHUNK; ++u) {                                       \
    const float wv = wc[u] * LOG2E;   /* prescale w: 8 muls vs 32 */      \
    float p0 = xc[0][u] * wv;                                             \
    float p1 = xc[1][u] * wv;                                             \
    float p2 = xc[2][u] * wv;                                             \
    float p3 = xc[3][u] * wv;                                             \
    float t0 = FAST_EXP2(__builtin_fabsf(p0));  /* v_exp_f32 w/ abs */    \
    float t1 = FAST_EXP2(__builtin_fabsf(p1));                            \
    float t2 = FAST_EXP2(__builtin_fabsf(p2));                            \
    float t3 = FAST_EXP2(__builtin_fabsf(p3));                            \
    num[0] += p0 * t0; den[0] += t0;                                      \
    num[1] += p1 * t1; den[1] += t1;                                      \
    num[2] += p2 * t2; den[2] += t2;                                      \
    num[3] += p3 * t3; den[3] += t3;                                      \
  }

  float num[4] = {0.f, 0.f, 0.f, 0.f};
  float den[4] = {0.f, 0.f, 0.f, 0.f};

  float xA[TILE_B][CHUNK], xB[TILE_B][CHUNK];
  float wA[CHUNK], wB[CHUNK];

  // Software pipeline in plain C: prefetch next chunk before computing the
  // current one; compiler inserts/schedules the waitcnts itself.
  XLOAD(xA, 0)
  WLOAD(wA, 0)

  for (int c = 0; c < NCHUNK; c += 2) {
    XLOAD(xB, c + 1)
    WLOAD(wB, c + 1)
    COMPUTE(xA, wA)
    if (c + 2 < NCHUNK) {
      XLOAD(xA, c + 2)
      WLOAD(wA, c + 2)
    }
    COMPUTE(xB, wB)
  }

  // ---- Cross-wave combine (single barrier) ----
  *(float4*)(&ps[ty][tx][0]) = make_float4(num[0], num[1], num[2], num[3]);
  *(float4*)(&ps[ty][tx][4]) = make_float4(den[0], den[1], den[2], den[3]);
  __syncthreads();

  if (ty == 0) {
    float n[4] = {0, 0, 0, 0}, d[4] = {0, 0, 0, 0};
#pragma unroll
    for (int q = 0; q < NW; ++q) {
      float4 a = *(const float4*)(&ps[q][tx][0]);
      float4 b2 = *(const float4*)(&ps[q][tx][4]);
      n[0] += a.x; n[1] += a.y; n[2] += a.z; n[3] += a.w;
      d[0] += b2.x; d[1] += b2.y; d[2] += b2.z; d[3] += b2.w;
    }
    const float LN2 = 0.6931471805599453f;
    const float scale = (float)IDIM * LN2;  // undo log2e, apply n=IDIM
    const int o = o0 + tx;
    const float bo = bias[o];
#pragma unroll
    for (int r = 0; r < 4; ++r)
      out[(size_t)(b0 + r) * ODIM + o] = scale * n[r] / d[r] + bo;
  }
}

extern "C" void kernel_launch(void* const* d_in, const int* in_sizes, int n_in,
                              void* d_out, int out_size, void* d_ws, size_t ws_size,
                              hipStream_t stream) {
  const float* x = (const float*)d_in[0];    // [256,1024] f32
  const float* w = (const float*)d_in[1];    // [1024,1024] f32
  const float* b = (const float*)d_in[2];    // [1024] f32
  float* out = (float*)d_out;                // [256,1024] f32

  dim3 grid(ODIM / TILE_O, BDIM / TILE_B);   // (16, 64) = 1024 blocks = 4/CU
  dim3 block(64, NW);                        // 512 threads = 8 waves
  stl_kernel<<<grid, block, 0, stream>>>(x, w, b, out);
}

// Round 3
// 89.631 us; speedup vs baseline: 1.1352x; 1.1352x over previous
//
#include <hip/hip_runtime.h>

// Problem dims (fixed by reference setup_inputs)
#define BDIM 256
#define IDIM 1024
#define ODIM 1024

#define TILE_O 64             // outputs per block (one per lane)
#define TILE_B 4              // batch rows per thread
#define NW 8                  // waves per block, each owns an i-eighth
#define QLEN (IDIM / NW)      // 128 i per wave
#define CHUNK 8               // i per w-prefetch chunk
#define NCHUNK (QLEN / CHUNK) // 16 chunks

typedef float v2f __attribute__((ext_vector_type(2)));
typedef float v4f __attribute__((ext_vector_type(4)));

#if __has_builtin(__builtin_amdgcn_exp2f)
#define FAST_EXP2(v) __builtin_amdgcn_exp2f(v)
#else
#define FAST_EXP2(v) exp2f(v)
#endif

__global__ __launch_bounds__(512, 4)
void stl_kernel(const float* __restrict__ x,
                const float* __restrict__ w,
                const float* __restrict__ bias,
                float* __restrict__ out) {
  __shared__ float xs[TILE_B][IDIM];   // 16 KB: 4 x rows, prescaled by log2e
  __shared__ float ps[NW][TILE_O][8];  // 16 KB: per-wave partials

  const int tx = threadIdx.x;          // 0..63 -> output column (lane)
  const int ty = threadIdx.y;          // 0..7  -> i-eighth (one wave each)
  const int tid = ty * 64 + tx;
  const int o0 = blockIdx.x * TILE_O;
  const int b0 = blockIdx.y * TILE_B;

  const float LOG2E = 1.4426950408889634f;  // folds 1/TEMPERATURE too

  // ---- Stage 4 x rows once (coalesced, prescaled). Barrier #1. ----
#pragma unroll
  for (int k = 0; k < 2; ++k) {
    int f = tid + k * 512;             // 0..1023 float4s
    int row = f >> 8;                  // 256 float4 per row
    int col = f & 255;
    float4 v = ((const float4*)(x + (size_t)(b0 + row) * IDIM))[col];
    v.x *= LOG2E; v.y *= LOG2E; v.z *= LOG2E; v.w *= LOG2E;
    ((float4*)(&xs[row][0]))[col] = v;
  }
  __syncthreads();

  const int qbase = ty * QLEN;
  const float* wp = w + (size_t)qbase * ODIM + o0 + tx;

  // Accumulators: one v2f (i-pair) per batch row -> all main-loop math is v_pk_*.
  v2f an0 = {0.f, 0.f}, an1 = {0.f, 0.f}, an2 = {0.f, 0.f}, an3 = {0.f, 0.f};
  v2f ad0 = {0.f, 0.f}, ad1 = {0.f, 0.f}, ad2 = {0.f, 0.f}, ad3 = {0.f, 0.f};

  // w chunk double buffer: 4 i-pairs each (v2f -> aligned VGPR pairs).
  v2f wA[CHUNK / 2], wB[CHUNK / 2];

#define WLOAD(dst, cc)                                                    \
  {                                                                       \
    const float* wq = wp + (size_t)((cc) * CHUNK) * ODIM;                 \
    _Pragma("unroll")                                                     \
    for (int u = 0; u < CHUNK / 2; ++u) {                                 \
      dst[u].x = wq[(size_t)(2 * u) * ODIM];                              \
      dst[u].y = wq[(size_t)(2 * u + 1) * ODIM];                          \
    }                                                                     \
  }

  // Process one 8-i chunk: x i-pairs come straight out of ds_read_b128
  // results (adjacent VGPRs), w i-pairs from the prefetched v2f buffer, so
  // p=x*w, num+=p*t, den+=t are v_pk_mul/v_pk_fma/v_pk_add. exp stays scalar
  // v_exp_f32 with the abs input modifier folded.
#define ROWP(acc_n, acc_d, xpair, wpair)                                  \
  {                                                                       \
    v2f p = (xpair) * (wpair);                                            \
    v2f t;                                                                \
    t.x = FAST_EXP2(__builtin_fabsf(p.x));                                \
    t.y = FAST_EXP2(__builtin_fabsf(p.y));                                \
    acc_n += p * t;                                                       \
    acc_d += t;                                                           \
  }

#define COMPUTE(wc, cc)                                                   \
  {                                                                       \
    const int jb = qbase + (cc) * CHUNK;                                  \
    _Pragma("unroll")                                                     \
    for (int h = 0; h < CHUNK / 4; ++h) {                                 \
      v4f xq0 = *(const v4f*)(&xs[0][jb + h * 4]);                        \
      v4f xq1 = *(const v4f*)(&xs[1][jb + h * 4]);                        \
      v4f xq2 = *(const v4f*)(&xs[2][jb + h * 4]);                        \
      v4f xq3 = *(const v4f*)(&xs[3][jb + h * 4]);                        \
      v2f wlo = wc[h * 2], whi = wc[h * 2 + 1];                           \
      ROWP(an0, ad0, __builtin_shufflevector(xq0, xq0, 0, 1), wlo)        \
      ROWP(an1, ad1, __builtin_shufflevector(xq1, xq1, 0, 1), wlo)        \
      ROWP(an2, ad2, __builtin_shufflevector(xq2, xq2, 0, 1), wlo)        \
      ROWP(an3, ad3, __builtin_shufflevector(xq3, xq3, 0, 1), wlo)        \
      ROWP(an0, ad0, __builtin_shufflevector(xq0, xq0, 2, 3), whi)        \
      ROWP(an1, ad1, __builtin_shufflevector(xq1, xq1, 2, 3), whi)        \
      ROWP(an2, ad2, __builtin_shufflevector(xq2, xq2, 2, 3), whi)        \
      ROWP(an3, ad3, __builtin_shufflevector(xq3, xq3, 2, 3), whi)        \
    }                                                                     \
  }

  // ---- Software-pipelined main loop: w loads for chunk c+1 issued before
  //      computing chunk c, so ~L2 latency hides under ~80 VALU ops. ----
  WLOAD(wA, 0)
  for (int c = 0; c < NCHUNK; c += 2) {
    WLOAD(wB, c + 1)
    COMPUTE(wA, c)
    WLOAD(wA, (c + 2) & (NCHUNK - 1))   // wrap: one harmless redundant reload
    COMPUTE(wB, c + 1)
  }

  // ---- Cross-wave combine (barrier #2) ----
  float num[4] = {an0.x + an0.y, an1.x + an1.y, an2.x + an2.y, an3.x + an3.y};
  float den[4] = {ad0.x + ad0.y, ad1.x + ad1.y, ad2.x + ad2.y, ad3.x + ad3.y};
  *(float4*)(&ps[ty][tx][0]) = make_float4(num[0], num[1], num[2], num[3]);
  *(float4*)(&ps[ty][tx][4]) = make_float4(den[0], den[1], den[2], den[3]);
  __syncthreads();

  if (ty == 0) {
    float n[4] = {0, 0, 0, 0}, d[4] = {0, 0, 0, 0};
#pragma unroll
    for (int q = 0; q < NW; ++q) {
      float4 a = *(const float4*)(&ps[q][tx][0]);
      float4 b2 = *(const float4*)(&ps[q][tx][4]);
      n[0] += a.x; n[1] += a.y; n[2] += a.z; n[3] += a.w;
      d[0] += b2.x; d[1] += b2.y; d[2] += b2.z; d[3] += b2.w;
    }
    const float LN2 = 0.6931471805599453f;
    const float scale = (float)IDIM * LN2;  // undo log2e, apply n=IDIM
    const int o = o0 + tx;
    const float bo = bias[o];
#pragma unroll
    for (int r = 0; r < 4; ++r)
      out[(size_t)(b0 + r) * ODIM + o] = scale * n[r] / d[r] + bo;
  }
}

extern "C" void kernel_launch(void* const* d_in, const int* in_sizes, int n_in,
                              void* d_out, int out_size, void* d_ws, size_t ws_size,
                              hipStream_t stream) {
  const float* x = (const float*)d_in[0];    // [256,1024] f32
  const float* w = (const float*)d_in[1];    // [1024,1024] f32
  const float* b = (const float*)d_in[2];    // [1024] f32
  float* out = (float*)d_out;                // [256,1024] f32

  dim3 grid(ODIM / TILE_O, BDIM / TILE_B);   // (16, 64) = 1024 blocks = 4/CU
  dim3 block(64, NW);                        // 512 threads = 8 waves
  stl_kernel<<<grid, block, 0, stream>>>(x, w, b, out);
}